// Round 5
// baseline (394.555 us; speedup 1.0000x reference)
//
#include <hip/hip_runtime.h>
#include <stdint.h>

// TankModel v5: B=8192 chains, T=4096 serial steps, 4 lanes/chain,
// block-systolic (4 timesteps/hop). Wall = per-chain elapsed (512 waves on
// 1024 SIMDs; occupancy/merging are NOT levers — lone-wave latency law:
//   elapsed/step ~= 2*I + 14*L   (I = wave inst/step, L = dep links/step)
// fits r0 (36,16->285), r6 (16,5->152), r7 (16.5,5->114).
// r8 (this): cut L 5 -> 3 exactly:
//  - t>=0 invariant (provable from setup parameter ranges: rate sums < 1,
//    P>=0, S0>=0 => all tank levels & inflows stay >=0) => max(t,0)=t.
//  - min-form: w' = t - sum max(r_j(t-h_j),0) - riN*t = min over 4 corner
//    lines s_i*t + c_i (exact: -max(a,0)=min(0,-a); mins distribute).
//    Y(outflow sum) = l0 - wn (off-spine). fl = riN*t (linear).
//  - intercept precompute: l_i = fma(s_i, w, e_i), e_i = fma(s_i, in, c_i);
//    all 4 steps' inflows are known at hop start -> e-prep off-spine.
//    Spine: w -> fma -> fmin -> fmin -> w'  (3 links, no max/sub chain).
// Staging (global->reg dbuf), p quad-broadcast, outbuf machinery: r7 verbatim.

__device__ __forceinline__ float quad_rot1(float x) {
    int xi = __builtin_bit_cast(int, x);
    // quad_perm: dest lane {0,1,2,3} <- src lane {3,0,1,2} of the same quad
    int r = __builtin_amdgcn_update_dpp(xi, xi, 0x93, 0xF, 0xF, false);
    return __builtin_bit_cast(float, r);
}

// Broadcast lane (s&3) of each quad to all 4 lanes. s folds to a constant
// under full unroll; DPPs sit in convergent straight-line code.
__device__ __forceinline__ float quad_bcast(float x, int s) {
    int xi = __builtin_bit_cast(int, x);
    int r;
    switch (s & 3) {
    case 0:  r = __builtin_amdgcn_update_dpp(xi, xi, 0x00, 0xF, 0xF, false); break;
    case 1:  r = __builtin_amdgcn_update_dpp(xi, xi, 0x55, 0xF, 0xF, false); break;
    case 2:  r = __builtin_amdgcn_update_dpp(xi, xi, 0xAA, 0xF, 0xF, false); break;
    default: r = __builtin_amdgcn_update_dpp(xi, xi, 0xFF, 0xF, 0xF, false); break;
    }
    return __builtin_bit_cast(float, r);
}

__global__ __launch_bounds__(64)
void tank_kernel(
    const float* __restrict__ P,
    const int*   __restrict__ lengths,
    const float* __restrict__ S0,
    const float* __restrict__ AreaP,
    const float* __restrict__ p_r1h1, const float* __restrict__ p_r1h2,
    const float* __restrict__ p_h1h1, const float* __restrict__ p_h1h2,
    const float* __restrict__ p_ri2,  const float* __restrict__ p_ro2,
    const float* __restrict__ p_h2,
    const float* __restrict__ p_ri3,  const float* __restrict__ p_ro3,
    const float* __restrict__ p_h3,
    const float* __restrict__ p_ri4,  const float* __restrict__ p_ro4,
    float* __restrict__ Out,
    int B, int T)
{
    __shared__ float4 outbuf[3 * 256];  // 3 x [16 rows][16 float4], XOR swizzle

    const int tid = threadIdx.x;
    const int g   = tid >> 2;          // group = chain row within block
    const int k   = tid & 3;           // tank role 0..3
    const int row = blockIdx.x * 16 + g;
    const int rowc = (row < B) ? row : (B - 1);
    const bool is0 = (k == 0);
    const bool is3 = (k == 3);
    const float zk = (k == 0) ? 0.0f : 1.0f;   // kills lane3->lane0 psum wrap

    const float v_r1h1 = p_r1h1[0], v_r1h2 = p_r1h2[0];
    const float v_h11 = p_h1h1[0], v_h12 = p_h1h2[0];
    const float v_ri2 = p_ri2[0], v_ro2 = p_ro2[0], v_h2 = p_h2[0];
    const float v_ri3 = p_ri3[0], v_ro3 = p_ro3[0], v_h3 = p_h3[0];
    const float v_ri4 = p_ri4[0], v_ro4 = p_ro4[0];
    const float scale = AreaP[0] * (1.0f / 3.6f);

    // Per-lane tank parameters (rA/hA = first outlet, rB/hB = second outlet
    // [tank1 only], riN = percolation to next tank).
    float rA = v_ro4, hA = 0.0f, rB = 0.0f, hB = 0.0f, riN = 0.0f;
    if (k == 0) { rA = v_r1h1; hA = v_h11; rB = v_r1h2; hB = v_h12; riN = v_ri2; }
    else if (k == 1) { rA = v_ro2; hA = v_h2; riN = v_ri3; }
    else if (k == 2) { rA = v_ro3; hA = v_h3; riN = v_ri4; }

    // Corner-line constants: w' = min_i(s_i * t + c_i)  (t = w + in >= 0)
    //   subsets S of active outlets {A,B}: slope = 1 - riN - sum r_S,
    //   intercept = sum r_S*h_S. Duplicated lines (rB=0) are harmless.
    const float s0c = 1.0f - riN;
    const float s1c = s0c - rA;
    const float s2c = s0c - rB;
    const float s3c = s1c - rB;
    const float c1c = rA * hA;
    const float c2c = rB * hB;
    const float c3c = c1c + c2c;

    float w = (k == 0) ? S0[0] : (k == 1) ? S0[1] : (k == 2) ? S0[2] : S0[3];

    int len = lengths[rowc];
    if (len > T) len = T;
    if (len < 0) len = 0;

    // Block-systolic state: this lane's 4 outflows / 4 running sums for the
    // block it just processed (rotated to the next lane at the next hop).
    float fl0 = 0.0f, fl1 = 0.0f, fl2 = 0.0f, fl3 = 0.0f;
    float ps0 = 0.0f, ps1 = 0.0f, ps2 = 0.0f, ps3 = 0.0f;
    const int ntiles = T / 64;         // 64 for T=4096 (even)

// One timestep. e0..e3 = per-step intercepts (precomputed off-spine),
// FF = riN*in (fl partial). Spine: w -> l(fma) -> fmin -> fmin -> w'.
// fl uses OLD w (computed before the w update). Y = l0 - wn (outflow sum;
// exact: l0 = (1-riN)*t). FREEZE (tile 0 only) holds w until first real hop.
#define STEP1(E0, E1, E2, E3, FF, QQ, FLOUT, PSOUT, FREEZE, hidx) do {  \
        float l0_ = fmaf(s0c, w, E0);                                   \
        float l1_ = fmaf(s1c, w, E1);                                   \
        float l2_ = fmaf(s2c, w, E2);                                   \
        float l3_ = fmaf(s3c, w, E3);                                   \
        float wn_ = fminf(fminf(l0_, l1_), fminf(l2_, l3_));            \
        FLOUT = fmaf(riN, w, FF);                                       \
        float Y_ = l0_ - wn_;                                           \
        w = (FREEZE) ? (((hidx) >= k) ? wn_ : w) : wn_;                 \
        PSOUT = fmaf(QQ, zk, Y_);                                       \
    } while (0)

// One hop = 4 timesteps of one block. All DPPs UNCONDITIONAL (convergent);
// lane-0 select afterwards on plain floats. Rotated values consumed with
// slack. e-prep (16 fma + 4 mul) depends only on hop-start inflows: off the
// w-spine entirely.
#define HOP4(CX, CY, CZ, CW, FREEZE, hidx) do {                         \
        float r0_ = quad_rot1(fl0);                                     \
        float r1_ = quad_rot1(fl1);                                     \
        float r2_ = quad_rot1(fl2);                                     \
        float r3_ = quad_rot1(fl3);                                     \
        float q0_ = quad_rot1(ps0);                                     \
        float q1_ = quad_rot1(ps1);                                     \
        float q2_ = quad_rot1(ps2);                                     \
        float q3_ = quad_rot1(ps3);                                     \
        float i0_ = is0 ? (CX) : r0_;                                   \
        float i1_ = is0 ? (CY) : r1_;                                   \
        float i2_ = is0 ? (CZ) : r2_;                                   \
        float i3_ = is0 ? (CW) : r3_;                                   \
        float e00_ = s0c * i0_;                                         \
        float e01_ = fmaf(s1c, i0_, c1c);                               \
        float e02_ = fmaf(s2c, i0_, c2c);                               \
        float e03_ = fmaf(s3c, i0_, c3c);                               \
        float f0_  = riN * i0_;                                         \
        float e10_ = s0c * i1_;                                         \
        float e11_ = fmaf(s1c, i1_, c1c);                               \
        float e12_ = fmaf(s2c, i1_, c2c);                               \
        float e13_ = fmaf(s3c, i1_, c3c);                               \
        float f1_  = riN * i1_;                                         \
        float e20_ = s0c * i2_;                                         \
        float e21_ = fmaf(s1c, i2_, c1c);                               \
        float e22_ = fmaf(s2c, i2_, c2c);                               \
        float e23_ = fmaf(s3c, i2_, c3c);                               \
        float f2_  = riN * i2_;                                         \
        float e30_ = s0c * i3_;                                         \
        float e31_ = fmaf(s1c, i3_, c1c);                               \
        float e32_ = fmaf(s2c, i3_, c2c);                               \
        float e33_ = fmaf(s3c, i3_, c3c);                               \
        float f3_  = riN * i3_;                                         \
        STEP1(e00_, e01_, e02_, e03_, f0_, q0_, fl0, ps0, FREEZE, hidx);\
        STEP1(e10_, e11_, e12_, e13_, f1_, q1_, fl1, ps1, FREEZE, hidx);\
        STEP1(e20_, e21_, e22_, e23_, f2_, q2_, fl2, ps2, FREEZE, hidx);\
        STEP1(e30_, e31_, e32_, e33_, f3_, q3_, fl3, ps3, FREEZE, hidx);\
    } while (0)

// Global -> reg tile stage (coalesced 16B/lane segments).
#define STAGE_LOAD(stN, mt) do {                                          \
        const float* src_ = P + (size_t)rowc * T + (mt) * 64;             \
        _Pragma("unroll")                                                 \
        for (int r = 0; r < 4; ++r)                                       \
            stN[r] = *reinterpret_cast<const float4*>(src_ + (4 * r + k) * 4); \
    } while (0)

// Coop-store out-tile mt with scale + length masking.
#define OUT_STORE(mt) do {                                                \
        const float4* ob_ = outbuf + ((mt) % 3) * 256;                    \
        const int col0_ = (mt) * 64;                                      \
        _Pragma("unroll")                                                 \
        for (int r = 0; r < 4; ++r) {                                     \
            float4 v_ = ob_[g * 16 + ((4 * r + k) ^ g)];                  \
            const int cb_ = col0_ + (4 * r + k) * 4;                      \
            float4 s_;                                                    \
            s_.x = (cb_ + 0 < len) ? v_.x * scale : 0.0f;                 \
            s_.y = (cb_ + 1 < len) ? v_.y * scale : 0.0f;                 \
            s_.z = (cb_ + 2 < len) ? v_.z * scale : 0.0f;                 \
            s_.w = (cb_ + 3 < len) ? v_.w * scale : 0.0f;                 \
            if (row < B)                                                  \
                *reinterpret_cast<float4*>(Out + (size_t)row * T + cb_) = s_; \
        }                                                                 \
    } while (0)

// 16 hops over one reg-staged tile. Hop j's p block = quad broadcast from
// lane j&3 of stN[j>>2] (all indices compile-time under full unroll).
// Lane3 completes one output block per hop -> outbuf.
#define TILE_BODY(FREEZE, h0, stN) do {                                   \
        _Pragma("unroll")                                                 \
        for (int j4 = 0; j4 < 16; ++j4) {                                 \
            const float4 pv_ = stN[j4 >> 2];                              \
            float px_ = quad_bcast(pv_.x, j4);                            \
            float py_ = quad_bcast(pv_.y, j4);                            \
            float pz_ = quad_bcast(pv_.z, j4);                            \
            float pw_ = quad_bcast(pv_.w, j4);                            \
            HOP4(px_, py_, pz_, pw_, FREEZE, j4);                         \
            const int b_ = (h0) + j4 - 3;                                 \
            if ((!(FREEZE) || b_ >= 0) && is3) {                          \
                float4* obp_ = outbuf + ((b_ >> 4) % 3) * 256;            \
                obp_[g * 16 + ((b_ & 15) ^ g)] =                          \
                    make_float4(ps0, ps1, ps2, ps3);                      \
            }                                                             \
        }                                                                 \
    } while (0)

    // ---- tile 0 (peeled: warm-up freeze active) ----
    float4 stA[4], stB[4];
    STAGE_LOAD(stA, 0);
    if (ntiles > 1) STAGE_LOAD(stB, 1);
    TILE_BODY(1, 0, stA);

    // ---- main tiles, pairwise (stB then stA), 1-tile prefetch distance ----
    #pragma clang loop unroll(disable)
    for (int m = 1; m + 1 < ntiles; m += 2) {
        STAGE_LOAD(stA, m + 1);
        if (m >= 3) OUT_STORE(m - 2);
        TILE_BODY(0, m * 16, stB);
        STAGE_LOAD(stB, m + 2);
        OUT_STORE(m - 1);
        TILE_BODY(0, (m + 1) * 16, stA);
    }

    // ---- peeled last tile (index ntiles-1, staged in stB) ----
    OUT_STORE(ntiles - 3);
    TILE_BODY(0, (ntiles - 1) * 16, stB);

    // Drain: 3 hops so lane3 completes blocks T/4-3 .. T/4-1. Lane0's p is
    // dead (its block indices >= T); rotated real data still propagates.
    {
        const int nb = T >> 2;
        #pragma unroll
        for (int d = 0; d < 3; ++d) {
            HOP4(0.0f, 0.0f, 0.0f, 0.0f, 0, 0);
            const int b_ = nb - 3 + d;
            if (is3) {
                float4* obp = outbuf + ((b_ >> 4) % 3) * 256;
                obp[g * 16 + ((b_ & 15) ^ g)] = make_float4(ps0, ps1, ps2, ps3);
            }
        }
    }
#undef HOP4
#undef STEP1
#undef TILE_BODY

    // Epilogue: store out-tiles ntiles-2, ntiles-1 (same-wave LDS order).
    OUT_STORE(ntiles - 2);
    OUT_STORE(ntiles - 1);
#undef OUT_STORE
#undef STAGE_LOAD
}

extern "C" void kernel_launch(void* const* d_in, const int* in_sizes, int n_in,
                              void* d_out, int out_size, void* d_ws, size_t ws_size,
                              hipStream_t stream) {
    const float* P        = (const float*)d_in[0];
    const int*   lengths  = (const int*)d_in[1];
    const float* S0       = (const float*)d_in[2];
    const float* Area     = (const float*)d_in[3];
    // d_in[4] = baseflow (unused by forward)
    const float* r1h1 = (const float*)d_in[5];
    const float* r1h2 = (const float*)d_in[6];
    const float* h1h1 = (const float*)d_in[7];
    const float* h1h2 = (const float*)d_in[8];
    const float* ri2  = (const float*)d_in[9];
    const float* ro2  = (const float*)d_in[10];
    const float* h2   = (const float*)d_in[11];
    const float* ri3  = (const float*)d_in[12];
    const float* ro3  = (const float*)d_in[13];
    const float* h3   = (const float*)d_in[14];
    const float* ri4  = (const float*)d_in[15];
    const float* ro4  = (const float*)d_in[16];
    float* out = (float*)d_out;

    const int B = in_sizes[1];
    const int T = in_sizes[0] / B;

    dim3 block(64);
    dim3 grid((B + 15) / 16);   // 16 chains per block (4 lanes/chain)
    hipLaunchKernelGGL(tank_kernel, grid, block, 0, stream,
                       P, lengths, S0, Area,
                       r1h1, r1h2, h1h1, h1h2,
                       ri2, ro2, h2, ri3, ro3, h3, ri4, ro4,
                       out, B, T);
}

// Round 6
// 365.583 us; speedup vs baseline: 1.0792x; 1.0792x over previous
//
#include <hip/hip_runtime.h>
#include <stdint.h>

// TankModel v6: B=8192 chains, T=4096 serial steps, 4 lanes/chain,
// block-systolic (4 timesteps/hop). Wall = per-chain elapsed (512 lone
// waves; occupancy is not a lever).
// r8 post-mortem: exposed stall is ~80 cyc/step CONSTANT under chain
// restructuring (5->3 links) => stall is NOT dep-chain; it tracks the 12
// DPPs/hop at ~25 cyc each — cross-lane DPP latency fully exposed because
// each DPP's consumer follows 1-2 insts behind at the hop top.
// r9 (this): r7's exact math + ONE-HOP-AHEAD rotate pipeline.
//  - rf0-3/rq0-3: fl/ps rotations issued right after each step produces
//    fl_i/ps_i; consumed by the NEXT hop (~80+ cyc of slack).
//  - pb0-3: next hop's p quad-broadcast issued at the hop top (reads stN
//    regs, no producer hazard), consumed next hop.
//  - dataflow identical to r7 (same values rotated, issued earlier);
//    warm-up freeze / drain / staging / outbuf machinery verbatim r7.

__device__ __forceinline__ float quad_rot1(float x) {
    int xi = __builtin_bit_cast(int, x);
    // quad_perm: dest lane {0,1,2,3} <- src lane {3,0,1,2} of the same quad
    int r = __builtin_amdgcn_update_dpp(xi, xi, 0x93, 0xF, 0xF, false);
    return __builtin_bit_cast(float, r);
}

// Broadcast lane (s&3) of each quad to all 4 lanes. s folds to a constant
// under full unroll; DPPs sit in convergent straight-line code.
__device__ __forceinline__ float quad_bcast(float x, int s) {
    int xi = __builtin_bit_cast(int, x);
    int r;
    switch (s & 3) {
    case 0:  r = __builtin_amdgcn_update_dpp(xi, xi, 0x00, 0xF, 0xF, false); break;
    case 1:  r = __builtin_amdgcn_update_dpp(xi, xi, 0x55, 0xF, 0xF, false); break;
    case 2:  r = __builtin_amdgcn_update_dpp(xi, xi, 0xAA, 0xF, 0xF, false); break;
    default: r = __builtin_amdgcn_update_dpp(xi, xi, 0xFF, 0xF, 0xF, false); break;
    }
    return __builtin_bit_cast(float, r);
}

__global__ __launch_bounds__(64)
void tank_kernel(
    const float* __restrict__ P,
    const int*   __restrict__ lengths,
    const float* __restrict__ S0,
    const float* __restrict__ AreaP,
    const float* __restrict__ p_r1h1, const float* __restrict__ p_r1h2,
    const float* __restrict__ p_h1h1, const float* __restrict__ p_h1h2,
    const float* __restrict__ p_ri2,  const float* __restrict__ p_ro2,
    const float* __restrict__ p_h2,
    const float* __restrict__ p_ri3,  const float* __restrict__ p_ro3,
    const float* __restrict__ p_h3,
    const float* __restrict__ p_ri4,  const float* __restrict__ p_ro4,
    float* __restrict__ Out,
    int B, int T)
{
    __shared__ float4 outbuf[3 * 256];  // 3 x [16 rows][16 float4], XOR swizzle

    const int tid = threadIdx.x;
    const int g   = tid >> 2;          // group = chain row within block
    const int k   = tid & 3;           // tank role 0..3
    const int row = blockIdx.x * 16 + g;
    const int rowc = (row < B) ? row : (B - 1);
    const bool is0 = (k == 0);
    const bool is3 = (k == 3);
    const float zk = (k == 0) ? 0.0f : 1.0f;   // kills lane3->lane0 psum wrap

    const float v_r1h1 = p_r1h1[0], v_r1h2 = p_r1h2[0];
    const float v_h11 = p_h1h1[0], v_h12 = p_h1h2[0];
    const float v_ri2 = p_ri2[0], v_ro2 = p_ro2[0], v_h2 = p_h2[0];
    const float v_ri3 = p_ri3[0], v_ro3 = p_ro3[0], v_h3 = p_h3[0];
    const float v_ri4 = p_ri4[0], v_ro4 = p_ro4[0];
    const float scale = AreaP[0] * (1.0f / 3.6f);

    // Per-lane tank constants (r7 form).
    float rA = v_ro4, kA = 0.0f, rB = 0.0f, kB = 0.0f, riN = 0.0f;
    if (k == 0) { rA = v_r1h1; kA = -v_r1h1 * v_h11; rB = v_r1h2; kB = -v_r1h2 * v_h12; riN = v_ri2; }
    else if (k == 1) { rA = v_ro2; kA = -v_ro2 * v_h2; riN = v_ri3; }
    else if (k == 2) { rA = v_ro3; kA = -v_ro3 * v_h3; riN = v_ri4; }

    float w = (k == 0) ? S0[0] : (k == 1) ? S0[1] : (k == 2) ? S0[2] : S0[3];

    int len = lengths[rowc];
    if (len > T) len = T;
    if (len < 0) len = 0;

    // Block-systolic state + one-hop-ahead pipeline registers.
    float fl0 = 0.0f, fl1 = 0.0f, fl2 = 0.0f, fl3 = 0.0f;
    float ps0 = 0.0f, ps1 = 0.0f, ps2 = 0.0f, ps3 = 0.0f;
    float rf0 = 0.0f, rf1 = 0.0f, rf2 = 0.0f, rf3 = 0.0f;  // rot(fl) of prev hop
    float rq0 = 0.0f, rq1 = 0.0f, rq2 = 0.0f, rq3 = 0.0f;  // rot(ps) of prev hop
    float pb0, pb1, pb2, pb3;                               // bcast p for next hop
    const int ntiles = T / 64;         // 64 for T=4096 (even)

// One timestep (r7 form). Spine: w->t->fma/max->add->sub->sub->w'.
// fl/ps written once per hop per slot; FREEZE (tile 0 only) holds w until
// this lane's first real hop (hidx >= k).
#define STEP1(IN, QQ, FLOUT, PSOUT, FREEZE, hidx) do {            \
        float t_  = w + (IN);                                     \
        float a1_ = fmaxf(fmaf(rA, t_, kA), 0.0f);                \
        float a2_ = fmaxf(fmaf(rB, t_, kB), 0.0f);                \
        float e_  = fmaxf(t_, 0.0f);                              \
        FLOUT = riN * e_;                                         \
        float Y_  = a1_ + a2_;                                    \
        float wn_ = (t_ - FLOUT) - Y_;                            \
        w = (FREEZE) ? (((hidx) >= k) ? wn_ : w) : wn_;           \
        PSOUT = fmaf(QQ, zk, Y_);                                 \
    } while (0)

// Global -> reg tile stage (coalesced 16B/lane segments).
#define STAGE_LOAD(stN, mt) do {                                          \
        const float* src_ = P + (size_t)rowc * T + (mt) * 64;             \
        _Pragma("unroll")                                                 \
        for (int r = 0; r < 4; ++r)                                       \
            stN[r] = *reinterpret_cast<const float4*>(src_ + (4 * r + k) * 4); \
    } while (0)

// Coop-store out-tile mt with scale + length masking.
#define OUT_STORE(mt) do {                                                \
        const float4* ob_ = outbuf + ((mt) % 3) * 256;                    \
        const int col0_ = (mt) * 64;                                      \
        _Pragma("unroll")                                                 \
        for (int r = 0; r < 4; ++r) {                                     \
            float4 v_ = ob_[g * 16 + ((4 * r + k) ^ g)];                  \
            const int cb_ = col0_ + (4 * r + k) * 4;                      \
            float4 s_;                                                    \
            s_.x = (cb_ + 0 < len) ? v_.x * scale : 0.0f;                 \
            s_.y = (cb_ + 1 < len) ? v_.y * scale : 0.0f;                 \
            s_.z = (cb_ + 2 < len) ? v_.z * scale : 0.0f;                 \
            s_.w = (cb_ + 3 < len) ? v_.w * scale : 0.0f;                 \
            if (row < B)                                                  \
                *reinterpret_cast<float4*>(Out + (size_t)row * T + cb_) = s_; \
        }                                                                 \
    } while (0)

// 16 hops over one reg-staged tile. Each hop:
//   1. consume pre-rotated rf/rq + pre-bcast pb (issued >= 1 hop earlier)
//   2. issue next hop's p-broadcast (full hop of slack before consumption)
//   3. 4 steps; rotate fl_i/ps_i right after they're produced
//   4. lane3 stores the completed block's psums
// stNx = next tile's st buffer (for j4==15's p-broadcast handoff).
#define TILE_BODY(FREEZE, h0, stN, stNx) do {                             \
        _Pragma("unroll")                                                 \
        for (int j4 = 0; j4 < 16; ++j4) {                                 \
            float i0_ = is0 ? pb0 : rf0;                                  \
            float i1_ = is0 ? pb1 : rf1;                                  \
            float i2_ = is0 ? pb2 : rf2;                                  \
            float i3_ = is0 ? pb3 : rf3;                                  \
            const float4 pv_ = (j4 < 15) ? (stN)[(j4 + 1) >> 2] : (stNx)[0]; \
            pb0 = quad_bcast(pv_.x, (j4 + 1) & 3);                        \
            pb1 = quad_bcast(pv_.y, (j4 + 1) & 3);                        \
            pb2 = quad_bcast(pv_.z, (j4 + 1) & 3);                        \
            pb3 = quad_bcast(pv_.w, (j4 + 1) & 3);                        \
            STEP1(i0_, rq0, fl0, ps0, FREEZE, j4);                        \
            rf0 = quad_rot1(fl0); rq0 = quad_rot1(ps0);                   \
            STEP1(i1_, rq1, fl1, ps1, FREEZE, j4);                        \
            rf1 = quad_rot1(fl1); rq1 = quad_rot1(ps1);                   \
            STEP1(i2_, rq2, fl2, ps2, FREEZE, j4);                        \
            rf2 = quad_rot1(fl2); rq2 = quad_rot1(ps2);                   \
            STEP1(i3_, rq3, fl3, ps3, FREEZE, j4);                        \
            rf3 = quad_rot1(fl3); rq3 = quad_rot1(ps3);                   \
            const int b_ = (h0) + j4 - 3;                                 \
            if ((!(FREEZE) || b_ >= 0) && is3) {                          \
                float4* obp_ = outbuf + ((b_ >> 4) % 3) * 256;            \
                obp_[g * 16 + ((b_ & 15) ^ g)] =                          \
                    make_float4(ps0, ps1, ps2, ps3);                      \
            }                                                             \
        }                                                                 \
    } while (0)

    // ---- tile 0 (peeled: warm-up freeze active) ----
    float4 stA[4], stB[4];
    STAGE_LOAD(stA, 0);
    if (ntiles > 1) STAGE_LOAD(stB, 1);
    // Prime the pipeline: hop 0 consumes rf=rq=0 (matches r7's rotate-of-
    // zero-state) and pb = block 0 = lane0's stA[0].
    pb0 = quad_bcast(stA[0].x, 0);
    pb1 = quad_bcast(stA[0].y, 0);
    pb2 = quad_bcast(stA[0].z, 0);
    pb3 = quad_bcast(stA[0].w, 0);
    TILE_BODY(1, 0, stA, stB);

    // ---- main tiles, pairwise (stB then stA), 1-tile prefetch distance ----
    #pragma clang loop unroll(disable)
    for (int m = 1; m + 1 < ntiles; m += 2) {
        STAGE_LOAD(stA, m + 1);
        if (m >= 3) OUT_STORE(m - 2);
        TILE_BODY(0, m * 16, stB, stA);
        STAGE_LOAD(stB, m + 2);
        OUT_STORE(m - 1);
        TILE_BODY(0, (m + 1) * 16, stA, stB);
    }

    // ---- peeled last tile (index ntiles-1, staged in stB). stNx=stB: the
    // j4==15 p-broadcast produces garbage, overwritten before drain. ----
    OUT_STORE(ntiles - 3);
    TILE_BODY(0, (ntiles - 1) * 16, stB, stB);

    // Drain: 3 hops so lane3 completes blocks T/4-3 .. T/4-1. Lane0's p is
    // dead (its block indices >= T); rotated real data still propagates.
    {
        pb0 = pb1 = pb2 = pb3 = 0.0f;
        const int nb = T >> 2;
        #pragma unroll
        for (int d = 0; d < 3; ++d) {
            float i0_ = is0 ? pb0 : rf0;
            float i1_ = is0 ? pb1 : rf1;
            float i2_ = is0 ? pb2 : rf2;
            float i3_ = is0 ? pb3 : rf3;
            STEP1(i0_, rq0, fl0, ps0, 0, 0);
            rf0 = quad_rot1(fl0); rq0 = quad_rot1(ps0);
            STEP1(i1_, rq1, fl1, ps1, 0, 0);
            rf1 = quad_rot1(fl1); rq1 = quad_rot1(ps1);
            STEP1(i2_, rq2, fl2, ps2, 0, 0);
            rf2 = quad_rot1(fl2); rq2 = quad_rot1(ps2);
            STEP1(i3_, rq3, fl3, ps3, 0, 0);
            rf3 = quad_rot1(fl3); rq3 = quad_rot1(ps3);
            const int b_ = nb - 3 + d;
            if (is3) {
                float4* obp = outbuf + ((b_ >> 4) % 3) * 256;
                obp[g * 16 + ((b_ & 15) ^ g)] = make_float4(ps0, ps1, ps2, ps3);
            }
        }
    }
#undef STEP1
#undef TILE_BODY

    // Epilogue: store out-tiles ntiles-2, ntiles-1 (same-wave LDS order).
    OUT_STORE(ntiles - 2);
    OUT_STORE(ntiles - 1);
#undef OUT_STORE
#undef STAGE_LOAD
}

extern "C" void kernel_launch(void* const* d_in, const int* in_sizes, int n_in,
                              void* d_out, int out_size, void* d_ws, size_t ws_size,
                              hipStream_t stream) {
    const float* P        = (const float*)d_in[0];
    const int*   lengths  = (const int*)d_in[1];
    const float* S0       = (const float*)d_in[2];
    const float* Area     = (const float*)d_in[3];
    // d_in[4] = baseflow (unused by forward)
    const float* r1h1 = (const float*)d_in[5];
    const float* r1h2 = (const float*)d_in[6];
    const float* h1h1 = (const float*)d_in[7];
    const float* h1h2 = (const float*)d_in[8];
    const float* ri2  = (const float*)d_in[9];
    const float* ro2  = (const float*)d_in[10];
    const float* h2   = (const float*)d_in[11];
    const float* ri3  = (const float*)d_in[12];
    const float* ro3  = (const float*)d_in[13];
    const float* h3   = (const float*)d_in[14];
    const float* ri4  = (const float*)d_in[15];
    const float* ro4  = (const float*)d_in[16];
    float* out = (float*)d_out;

    const int B = in_sizes[1];
    const int T = in_sizes[0] / B;

    dim3 block(64);
    dim3 grid((B + 15) / 16);   // 16 chains per block (4 lanes/chain)
    hipLaunchKernelGGL(tank_kernel, grid, block, 0, stream,
                       P, lengths, S0, Area,
                       r1h1, r1h2, h1h1, h1h2,
                       ri2, ro2, h2, ri3, ro3, h3, ri4, ro4,
                       out, B, T);
}